// Round 13
// baseline (219.968 us; speedup 1.0000x reference)
//
#include <hip/hip_runtime.h>
#include <math.h>

typedef unsigned short u16;
typedef unsigned int u32;
typedef __attribute__((ext_vector_type(8))) short short8;
typedef __attribute__((ext_vector_type(8))) float f32x8;
typedef __attribute__((ext_vector_type(4))) float f32x4;
typedef __attribute__((ext_vector_type(2))) unsigned int uint2v;

#define NEG_BIG   (-4294967296.0f)   /* float32(-2^32+1) */
#define NEG_INF_F (-__builtin_inff())

/* ---- workspace layout (float offsets) ---- */
#define WS_S    0        /* [80][64] f32: w1[:,0:64]+w1[:,128:192] (for c0) */
#define WS_W1T  5120     /* [288][200] f32 mlp_w1^T */
#define WS_W2T  62720    /* [200][80]  f32 mlp_w2^T */
#define WS_W3T  78720    /* [80][2]    f32 mlp_w3^T */
#define WS_W3P  78880    /* [48] f32 att_w3 zero-padded */
#define WS_WF1F 78928    /* 10240 bf16: W1cat frags [5 nt][4 ks][64 lane][8] */
#define WS_WF2F 84048    /* 4608 bf16: W2cat frags [3 nt][3 ks][64 lane][8] */
#define WS_XF   86352    /* [4096][288] f32 feature rows (kernel A -> kernel B) */

/* HW packed f32->bf16 RNE (T12/m240: no builtin on gfx950, inline asm is the recipe) */
__device__ __forceinline__ u32 f2bf2(float lo, float hi) {
    u32 r;
    asm("v_cvt_pk_bf16_f32 %0, %1, %2" : "=v"(r) : "v"(lo), "v"(hi));
    return r;
}
__device__ __forceinline__ u16 f2bf(float f) {
    u32 r;
    asm("v_cvt_pk_bf16_f32 %0, %1, %1" : "=v"(r) : "v"(f));
    return (u16)r;
}
__device__ __forceinline__ float bf2f(u16 h) {
    union { u32 u; float f; } v; v.u = ((u32)h) << 16;
    return v.f;
}
/* sigmoid = rcp(1 + 2^(-x*log2e)) : 4 VALU instrs, ~1 ULP */
__device__ __forceinline__ float fsigmoid(float x) {
    float e, r;
    float t = x * -1.44269504088896f;
    asm("v_exp_f32 %0, %1" : "=v"(e) : "v"(t));
    float d = 1.0f + e;
    asm("v_rcp_f32 %0, %1" : "=v"(r) : "v"(d));
    return r;
}
__device__ __forceinline__ short8 mulqf(short8 a, f32x8 qf) {
    union { u32 w[4]; short8 s; } r;
    #pragma unroll
    for (int j = 0; j < 4; ++j) {
        float p0 = bf2f((u16)a[2*j])   * qf[2*j];
        float p1 = bf2f((u16)a[2*j+1]) * qf[2*j+1];
        r.w[j] = f2bf2(p0, p1);
    }
    return r.s;
}
__device__ __forceinline__ f32x4 mfma16(short8 a, short8 b, f32x4 c) {
    return __builtin_amdgcn_mfma_f32_16x16x32_bf16(a, b, c, 0, 0, 0);
}

__global__ __launch_bounds__(256) void prep_kernel(
    const float* __restrict__ att_w1,
    const float* __restrict__ att_w2,
    const float* __restrict__ att_w3,
    const float* __restrict__ mlp_w1,
    const float* __restrict__ mlp_w2,
    const float* __restrict__ mlp_w3,
    float* __restrict__ ws)
{
    int idx = blockIdx.x * 256 + threadIdx.x;
    if (idx < 5120) {
        int h = idx >> 6, j = idx & 63;
        ws[WS_S + idx] = att_w1[h*256 + j] + att_w1[h*256 + 128 + j];
    } else if (idx < 62720) {
        int r = idx - 5120;            /* r = k*200 + t */
        int k = r / 200, t = r - k*200;
        ws[WS_W1T + r] = mlp_w1[t*288 + k];
    } else if (idx < 78720) {
        int r = idx - 62720;           /* r = k*80 + g */
        int k = r / 80, g = r - k*80;
        ws[WS_W2T + r] = mlp_w2[g*200 + k];
    } else if (idx < 78880) {
        int r = idx - 78720;           /* r = k*2 + o */
        int k = r >> 1, o = r & 1;
        ws[WS_W3T + r] = mlp_w3[o*80 + k];
    } else if (idx < 78928) {
        int g = idx - 78880;
        ws[WS_W3P + g] = (g < 40) ? att_w3[g] : 0.0f;
    } else if (idx < 89168) {
        /* W1cat fragments: Xcat(200x128) @ W1cat(128x80)
           k<64: beh rows -> w1[:,64:128]-w1[:,128:192]; k>=64: q*beh -> w1[:,192:256] */
        int e  = idx - 78928;
        int nt = e >> 11;
        int ks = (e >> 9) & 3;
        int ln = (e >> 3) & 63;
        int j  = e & 7;
        int n = nt*16 + (ln & 15);
        int k = ks*32 + (ln >> 4)*8 + j;
        float val = (k < 64)
            ? (att_w1[n*256 + 64 + k] - att_w1[n*256 + 128 + k])
            : att_w1[n*256 + 192 + (k - 64)];
        ((u16*)(ws + WS_WF1F))[e] = f2bf(val);
    } else if (idx < 93776) {
        /* W2cat fragments: S1(200x80,pad96) @ W2cat(96x48): W2cat[k][n]=att_w2[n*80+k] */
        int e  = idx - 89168;
        int nt = e / 1536;
        int ks = (e / 512) % 3;
        int ln = (e >> 3) & 63;
        int j  = e & 7;
        int n = nt*16 + (ln & 15);
        int k = ks*32 + (ln >> 4)*8 + j;
        float val = (n < 40 && k < 80) ? att_w2[n*80 + k] : 0.0f;
        ((u16*)(ws + WS_WF2F))[e] = f2bf(val);
    }
}

/* ---- Kernel A: gather + attention + softmax + pooling -> feature row X[b][288] ----
   8-wave (512-thread) block: LDS ~63 KB -> 2 blocks/CU = 16 waves/CU (vs R11's 12).
   Per-thread register demand ~85-90 (R11 measured 84) <= 128 cap of (512,2).
   R12 lesson: WF2-in-regs pushes demand past 128 and spills -- WF2 stays in LDS. */
__global__ __launch_bounds__(512, 2) void din_kernel(
    const int* __restrict__ uid, const int* __restrict__ gid, const int* __restrict__ cid,
    const int* __restrict__ gid_his, const int* __restrict__ cid_his, const int* __restrict__ masks,
    const float* __restrict__ user_emb, const float* __restrict__ good_emb, const float* __restrict__ cat_emb,
    const float* __restrict__ att_b1, const float* __restrict__ att_b2, const float* __restrict__ att_b3,
    const float* __restrict__ ws, float* __restrict__ Xg)
{
    /* Xc[200 rows][64 bf16] with 16B-slot XOR swizzle: slot' = slot ^ (row&7)  (25600 B) */
    __shared__ u16 Xc[200*64];
    /* per-wave S1 scratch: 8 waves x [16 rows][104 bf16] = 26624 B */
    __shared__ u16 scr[8*1664];
    /* WF2 fragments staged in LDS: [9 frag][64 lane][8 bf16] = 9216 B */
    __shared__ u16 wf2_sh[9*512];
    __shared__ float q_sh[64];
    __shared__ float c0_sh[80];
    __shared__ float sp_sh[256];
    __shared__ float scal_sh[2];
    /* total ~63.0 KB <= 64 KB static limit; 2 blocks/CU */

    /* overlays into scr (only live after the tile loop is done): 1024 floats = 4 KB */
    float* redA  = (float*)scr;       /* [8 qq][64 col] */
    float* redU  = redA + 512;        /* [8 qq][64 col] */

    const int b    = blockIdx.x;
    const int tid  = threadIdx.x;
    const int lane = tid & 63;
    const int wv   = tid >> 6;        /* 0..7 */
    const int lrow = lane & 15;
    const int lgrp = lane >> 4;

    const int* gh = gid_his + b*200;
    const int* ch = cid_his + b*200;

    /* ---- Preload W1cat fragments into registers (loop-invariant): 20 x 16B = 80 VGPR ---- */
    short8 wf1r[20];
    {
        const short8* WF1 = (const short8*)(ws + WS_WF1F);
        #pragma unroll
        for (int i = 0; i < 20; ++i) wf1r[i] = WF1[i*64 + lane];
    }
    /* stage WF2 fragments into LDS (2304 u32) */
    {
        const u32* src = (const u32*)(ws + WS_WF2F);
        u32* dst = (u32*)wf2_sh;
        #pragma unroll
        for (int i = 0; i < 4; ++i) dst[i*512 + tid] = src[i*512 + tid];
        if (tid < 256) dst[2048 + tid] = src[2048 + tid];
    }

    /* ---- Phase 0/1 fused: gather -> bf16 -> Xc (swizzled); 3200 quad-loads ---- */
    #pragma unroll
    for (int it = 0; it < 6; ++it) {
        int idx = it*512 + tid;
        int l = idx >> 4, c = idx & 15;
        const float* src = (c < 8)
            ? (good_emb + (size_t)gh[l]*32 + (c & 7)*4)
            : (cat_emb  + (size_t)ch[l]*32 + (c & 7)*4);
        float4 v = *(const float4*)src;
        uint2v pk;
        pk[0] = f2bf2(v.x, v.y);
        pk[1] = f2bf2(v.z, v.w);
        int byteoff = l*128 + ((((c >> 1) ^ (l & 7)) << 4)) + ((c & 1) << 3);
        *((uint2v*)((char*)Xc + byteoff)) = pk;
    }
    if (tid < 128) {
        int idx = 3072 + tid;
        int l = idx >> 4, c = idx & 15;
        const float* src = (c < 8)
            ? (good_emb + (size_t)gh[l]*32 + (c & 7)*4)
            : (cat_emb  + (size_t)ch[l]*32 + (c & 7)*4);
        float4 v = *(const float4*)src;
        uint2v pk;
        pk[0] = f2bf2(v.x, v.y);
        pk[1] = f2bf2(v.z, v.w);
        int byteoff = l*128 + ((((c >> 1) ^ (l & 7)) << 4)) + ((c & 1) << 3);
        *((uint2v*)((char*)Xc + byteoff)) = pk;
    }
    if (tid < 64) {
        q_sh[tid] = (tid < 32) ? good_emb[(size_t)gid[b]*32 + tid]
                               : cat_emb[(size_t)cid[b]*32 + (tid - 32)];
    }
    if (tid >= 200 && tid < 256) sp_sh[tid] = NEG_INF_F;
    __syncthreads();

    /* c0[h] = b1[h] + sum_j q_j*(W1[h,j]+W1[h,128+j]); float4 loads */
    if (tid < 80) {
        const float4* Sw = (const float4*)(ws + WS_S + tid*64);
        const float4* q4 = (const float4*)q_sh;
        float u0 = 0.f, u1 = 0.f;
        #pragma unroll
        for (int j = 0; j < 16; j += 2) {
            float4 w0 = Sw[j],   qv0 = q4[j];
            float4 w1 = Sw[j+1], qv1 = q4[j+1];
            u0 += w0.x*qv0.x + w0.y*qv0.y + w0.z*qv0.z + w0.w*qv0.w;
            u1 += w1.x*qv1.x + w1.y*qv1.y + w1.z*qv1.z + w1.w*qv1.w;
        }
        c0_sh[tid] = att_b1[tid] + u0 + u1;
    }
    __syncthreads();

    /* ---- Phase 2: per-M-tile attention MLP via MFMA; 13 tiles over 8 waves ---- */
    f32x8 qf0, qf1;
    #pragma unroll
    for (int j = 0; j < 8; ++j) {
        qf0[j] = q_sh[lgrp*8 + j];
        qf1[j] = q_sh[32 + lgrp*8 + j];
    }
    float c0v[5];
    #pragma unroll
    for (int nt = 0; nt < 5; ++nt) c0v[nt] = c0_sh[nt*16 + lrow];
    float b2v[3], w3c[3];
    #pragma unroll
    for (int nt = 0; nt < 3; ++nt) {
        int col = nt*16 + lrow;
        b2v[nt] = (col < 40) ? att_b2[col] : 0.0f;
        w3c[nt] = ws[WS_W3P + col];
    }
    const float bias3 = att_b3[0];

    u16* scr_w = scr + wv*1664;

    /* zero-pad S1 cols 80..95 once (never overwritten by S1 stores) */
    {
        uint2v z; z[0] = 0u; z[1] = 0u;
        *((uint2v*)(scr_w + lrow*104 + 80 + lgrp*4)) = z;
    }

    for (int t = wv; t < 13; t += 8) {
        const int m0 = (t == 12) ? 184 : (t << 4);   /* tile 12 overlaps tile 11: benign same-value race */
        const int m  = m0 + lrow;

        /* A fragments: beh (ks 0,1 from LDS), q*beh (ks 2,3 in-register) */
        short8 A0, A1;
        {
            int sl0 = (0 + lgrp) ^ (m & 7);
            int sl1 = (4 + lgrp) ^ (m & 7);
            A0 = *(const short8*)((const char*)Xc + m*128 + (sl0 << 4));
            A1 = *(const short8*)((const char*)Xc + m*128 + (sl1 << 4));
        }
        short8 A2 = mulqf(A0, qf0);
        short8 A3 = mulqf(A1, qf1);

        /* layer 1: S1(16x80) = sigmoid(Xcat @ W1cat + c0) -> scratch bf16 */
        #pragma unroll
        for (int nt = 0; nt < 5; ++nt) {
            f32x4 acc = {0.f, 0.f, 0.f, 0.f};
            acc = mfma16(A0, wf1r[nt*4 + 0], acc);
            acc = mfma16(A1, wf1r[nt*4 + 1], acc);
            acc = mfma16(A2, wf1r[nt*4 + 2], acc);
            acc = mfma16(A3, wf1r[nt*4 + 3], acc);
            #pragma unroll
            for (int r = 0; r < 4; ++r) {
                float s1v = fsigmoid(acc[r] + c0v[nt]);
                scr_w[(lgrp*4 + r)*104 + nt*16 + lrow] = f2bf(s1v);
            }
        }

        /* layer 2: S2(16x48) accumulators stay in registers */
        short8 B0 = *(const short8*)(scr_w + lrow*104 +  0 + lgrp*8);
        short8 B1 = *(const short8*)(scr_w + lrow*104 + 32 + lgrp*8);
        short8 B2 = *(const short8*)(scr_w + lrow*104 + 64 + lgrp*8);
        f32x4 acc2[3];
        #pragma unroll
        for (int nt = 0; nt < 3; ++nt) {
            f32x4 acc = {0.f, 0.f, 0.f, 0.f};
            acc = mfma16(B0, *(const short8*)(wf2_sh + ((nt*3 + 0)*64 + lane)*8), acc);
            acc = mfma16(B1, *(const short8*)(wf2_sh + ((nt*3 + 1)*64 + lane)*8), acc);
            acc = mfma16(B2, *(const short8*)(wf2_sh + ((nt*3 + 2)*64 + lane)*8), acc);
            acc2[nt] = acc;
        }

        /* layer 3 fully in-register: partial = sum_nt sigmoid(acc2[nt][r]+b2)*w3;
           reduce over 16 lanes (cols) via xor-shfl 1,2,4,8 */
        float v3p[4];
        #pragma unroll
        for (int r = 0; r < 4; ++r) {
            float p = fsigmoid(acc2[0][r] + b2v[0]) * w3c[0]
                    + fsigmoid(acc2[1][r] + b2v[1]) * w3c[1]
                    + fsigmoid(acc2[2][r] + b2v[2]) * w3c[2];
            p += __shfl_xor(p, 1);
            p += __shfl_xor(p, 2);
            p += __shfl_xor(p, 4);
            p += __shfl_xor(p, 8);
            v3p[r] = p;
        }
        if (lrow == 0) {
            #pragma unroll
            for (int r = 0; r < 4; ++r) {
                int mm = m0 + lgrp*4 + r;
                int mk = masks[b*200 + mm];
                sp_sh[mm] = mk ? (v3p[r] + bias3) : NEG_BIG;
            }
        }
    }
    __syncthreads();

    /* ---- Phase 3: masked softmax over l ---- */
    if (tid < 64) {
        float mv = fmaxf(fmaxf(sp_sh[tid], sp_sh[tid+64]), fmaxf(sp_sh[tid+128], sp_sh[tid+192]));
        #pragma unroll
        for (int off = 32; off > 0; off >>= 1) mv = fmaxf(mv, __shfl_down(mv, off));
        if (tid == 0) scal_sh[0] = mv;
    }
    __syncthreads();
    if (tid < 256) {
        float mx = scal_sh[0];
        float sm = sp_sh[tid];
        float ev = (tid < 200) ? __expf(sm - mx) : 0.0f;
        sp_sh[tid] = ev;
    }
    __syncthreads();
    if (tid < 64) {
        float s = (sp_sh[tid] + sp_sh[tid+64]) + (sp_sh[tid+128] + sp_sh[tid+192]);
        #pragma unroll
        for (int off = 32; off > 0; off >>= 1) s += __shfl_down(s, off);
        if (tid == 0) scal_sh[1] = s;
    }
    __syncthreads();

    /* ---- Phase 4: pooling att (unnormalized) and ubs; paired u32 reads from Xc ---- */
    if (tid < 256) {
        int j2 = tid & 31;            /* column pair: cols 2j2, 2j2+1 */
        int qq = tid >> 5;            /* 8 row-groups of 25 */
        int slot = j2 >> 2;           /* logical 16B slot = (2j2)>>3 */
        int inb  = (j2 & 3) << 2;     /* byte within slot */
        float a0 = 0.f, a1 = 0.f, u0 = 0.f, u1 = 0.f;
        #pragma unroll 5
        for (int mm = qq*25; mm < qq*25 + 25; ++mm) {
            u32 pr = *(const u32*)((const char*)Xc + mm*128 + (((slot ^ (mm & 7)) << 4)) + inb);
            float b0 = bf2f((u16)pr);
            float b1_ = bf2f((u16)(pr >> 16));
            float w = sp_sh[mm];
            a0 += w*b0; a1 += w*b1_;
            u0 += b0;   u1 += b1_;
        }
        redA[qq*64 + 2*j2]     = a0;
        redA[qq*64 + 2*j2 + 1] = a1;
        redU[qq*64 + 2*j2]     = u0;
        redU[qq*64 + 2*j2 + 1] = u1;
    }
    __syncthreads();

    /* ---- write feature row X[b][288] ---- */
    float inv = 1.0f / scal_sh[1];
    if (tid < 64) {
        float att = 0.f, ub = 0.f;
        #pragma unroll
        for (int qq = 0; qq < 8; ++qq) {
            att += redA[qq*64 + tid];
            ub  += redU[qq*64 + tid];
        }
        att *= inv;
        float qv = q_sh[tid];
        float* xr = Xg + (size_t)b*288;
        xr[32  + tid] = qv;
        xr[96  + tid] = ub;
        xr[160 + tid] = ub * qv;
        xr[224 + tid] = att;
    }
    if (tid >= 64 && tid < 96) {
        Xg[(size_t)b*288 + (tid - 64)] = user_emb[(size_t)uid[b]*32 + (tid - 64)];
    }
}

/* ---- Kernel B: final MLP 288 -> 200 -> 80 -> 2, 8 rows/block x 512 blocks ---- */
__global__ __launch_bounds__(256) void mlp_kernel(
    const float* __restrict__ ws,
    const float* __restrict__ mlp_b1, const float* __restrict__ mlp_b2, const float* __restrict__ mlp_b3,
    const float* __restrict__ pa1, const float* __restrict__ pa2,
    float* __restrict__ out)
{
    __shared__ float h1_sh[8*204];
    __shared__ float h2_sh[8*81];

    const int tid = threadIdx.x;
    const int r0  = blockIdx.x * 8;
    const float* Xg  = ws + WS_XF;
    const float* w1T = ws + WS_W1T;
    const float* w2T = ws + WS_W2T;
    const float* w3T = ws + WS_W3T;

    /* layer 1: thread = neuron n, register-block over 8 rows */
    {
        int n = (tid < 200) ? tid : 199;
        float bias = mlp_b1[n];
        float acc[8];
        #pragma unroll
        for (int r = 0; r < 8; ++r) acc[r] = bias;
        for (int k = 0; k < 288; k += 4) {
            float w0 = w1T[(k+0)*200 + n];
            float w1 = w1T[(k+1)*200 + n];
            float w2 = w1T[(k+2)*200 + n];
            float w3 = w1T[(k+3)*200 + n];
            #pragma unroll
            for (int r = 0; r < 8; ++r) {
                const float4 xv = *(const float4*)(Xg + (size_t)(r0 + r)*288 + k);
                acc[r] += xv.x*w0 + xv.y*w1 + xv.z*w2 + xv.w*w3;
            }
        }
        if (tid < 200) {
            float a = pa1[n];
            #pragma unroll
            for (int r = 0; r < 8; ++r) {
                float v = acc[r];
                h1_sh[r*204 + n] = (v >= 0.f) ? v : a*v;
            }
        }
    }
    __syncthreads();

    /* layer 2: 160 threads: g = tid%80, row-half = (tid/80)*4 (4 rows each) */
    if (tid < 160) {
        int g  = (tid < 80) ? tid : tid - 80;
        int rh = (tid < 80) ? 0 : 4;
        float bias = mlp_b2[g];
        float acc[4];
        #pragma unroll
        for (int r = 0; r < 4; ++r) acc[r] = bias;
        for (int k = 0; k < 200; k += 4) {
            float w0 = w2T[(k+0)*80 + g];
            float w1 = w2T[(k+1)*80 + g];
            float w2 = w2T[(k+2)*80 + g];
            float w3 = w2T[(k+3)*80 + g];
            #pragma unroll
            for (int r = 0; r < 4; ++r) {
                const float4 xv = *(const float4*)(&h1_sh[(rh + r)*204 + k]);
                acc[r] += xv.x*w0 + xv.y*w1 + xv.z*w2 + xv.w*w3;
            }
        }
        float a = pa2[g];
        #pragma unroll
        for (int r = 0; r < 4; ++r) {
            float v = acc[r];
            h2_sh[(rh + r)*81 + g] = (v >= 0.f) ? v : a*v;
        }
    }
    __syncthreads();

    /* layer 3: 16 threads: (row, o) */
    if (tid < 16) {
        int r = tid >> 1, o = tid & 1;
        float acc = mlp_b3[o];
        #pragma unroll 8
        for (int k = 0; k < 80; ++k) acc += h2_sh[r*81 + k] * w3T[k*2 + o];
        out[(size_t)(r0 + r)*2 + o] = acc;
    }
}

extern "C" void kernel_launch(void* const* d_in, const int* in_sizes, int n_in,
                              void* d_out, int out_size, void* d_ws, size_t ws_size,
                              hipStream_t stream) {
    const int*   uid      = (const int*)d_in[0];
    const int*   gid      = (const int*)d_in[1];
    const int*   cid      = (const int*)d_in[2];
    const int*   gid_his  = (const int*)d_in[3];
    const int*   cid_his  = (const int*)d_in[4];
    const int*   masks    = (const int*)d_in[5];
    const float* user_emb = (const float*)d_in[6];
    const float* good_emb = (const float*)d_in[7];
    const float* cat_emb  = (const float*)d_in[8];
    const float* att_w1   = (const float*)d_in[9];
    const float* att_b1   = (const float*)d_in[10];
    const float* att_w2   = (const float*)d_in[11];
    const float* att_b2   = (const float*)d_in[12];
    const float* att_w3   = (const float*)d_in[13];
    const float* att_b3   = (const float*)d_in[14];
    const float* mlp_w1   = (const float*)d_in[15];
    const float* mlp_b1   = (const float*)d_in[16];
    const float* mlp_w2   = (const float*)d_in[17];
    const float* mlp_b2   = (const float*)d_in[18];
    const float* mlp_w3   = (const float*)d_in[19];
    const float* mlp_b3   = (const float*)d_in[20];
    const float* pa1      = (const float*)d_in[21];
    const float* pa2      = (const float*)d_in[22];
    float* ws   = (float*)d_ws;
    float* outp = (float*)d_out;

    hipLaunchKernelGGL(prep_kernel, dim3(367), dim3(256), 0, stream,
                       att_w1, att_w2, att_w3, mlp_w1, mlp_w2, mlp_w3, ws);
    hipLaunchKernelGGL(din_kernel, dim3(4096), dim3(512), 0, stream,
                       uid, gid, cid, gid_his, cid_his, masks,
                       user_emb, good_emb, cat_emb,
                       att_b1, att_b2, att_b3,
                       ws, ws + WS_XF);
    hipLaunchKernelGGL(mlp_kernel, dim3(512), dim3(256), 0, stream,
                       ws, mlp_b1, mlp_b2, mlp_b3, pa1, pa2, outp);
}

// Round 14
// 153.623 us; speedup vs baseline: 1.4319x; 1.4319x over previous
//
#include <hip/hip_runtime.h>
#include <math.h>

typedef unsigned short u16;
typedef unsigned int u32;
typedef __attribute__((ext_vector_type(8))) short short8;
typedef __attribute__((ext_vector_type(8))) float f32x8;
typedef __attribute__((ext_vector_type(4))) float f32x4;
typedef __attribute__((ext_vector_type(2))) unsigned int uint2v;

#define NEG_BIG   (-4294967296.0f)   /* float32(-2^32+1) */
#define NEG_INF_F (-__builtin_inff())

/* ---- workspace layout (float offsets) ---- */
#define WS_S    0        /* [80][64] f32: w1[:,0:64]+w1[:,128:192] (for c0) */
#define WS_W1T  5120     /* [288][200] f32 mlp_w1^T */
#define WS_W2T  62720    /* [200][80]  f32 mlp_w2^T */
#define WS_W3T  78720    /* [80][2]    f32 mlp_w3^T */
#define WS_W3P  78880    /* [48] f32 att_w3 zero-padded */
#define WS_WF1F 78928    /* 10240 bf16: W1cat frags [5 nt][4 ks][64 lane][8] */
#define WS_WF2F 84048    /* 4608 bf16: W2cat frags [3 nt][3 ks][64 lane][8] */
#define WS_XF   86352    /* [4096][288] f32 feature rows (kernel A -> kernel B) */

/* HW packed f32->bf16 RNE (T12/m240: no builtin on gfx950, inline asm is the recipe) */
__device__ __forceinline__ u32 f2bf2(float lo, float hi) {
    u32 r;
    asm("v_cvt_pk_bf16_f32 %0, %1, %2" : "=v"(r) : "v"(lo), "v"(hi));
    return r;
}
__device__ __forceinline__ u16 f2bf(float f) {
    u32 r;
    asm("v_cvt_pk_bf16_f32 %0, %1, %1" : "=v"(r) : "v"(f));
    return (u16)r;
}
__device__ __forceinline__ float bf2f(u16 h) {
    union { u32 u; float f; } v; v.u = ((u32)h) << 16;
    return v.f;
}
/* sigmoid = rcp(1 + 2^(-x*log2e)) : 4 VALU instrs, ~1 ULP */
__device__ __forceinline__ float fsigmoid(float x) {
    float e, r;
    float t = x * -1.44269504088896f;
    asm("v_exp_f32 %0, %1" : "=v"(e) : "v"(t));
    float d = 1.0f + e;
    asm("v_rcp_f32 %0, %1" : "=v"(r) : "v"(d));
    return r;
}
__device__ __forceinline__ short8 mulqf(short8 a, f32x8 qf) {
    union { u32 w[4]; short8 s; } r;
    #pragma unroll
    for (int j = 0; j < 4; ++j) {
        float p0 = bf2f((u16)a[2*j])   * qf[2*j];
        float p1 = bf2f((u16)a[2*j+1]) * qf[2*j+1];
        r.w[j] = f2bf2(p0, p1);
    }
    return r.s;
}
__device__ __forceinline__ f32x4 mfma16(short8 a, short8 b, f32x4 c) {
    return __builtin_amdgcn_mfma_f32_16x16x32_bf16(a, b, c, 0, 0, 0);
}

__global__ __launch_bounds__(256) void prep_kernel(
    const float* __restrict__ att_w1,
    const float* __restrict__ att_w2,
    const float* __restrict__ att_w3,
    const float* __restrict__ mlp_w1,
    const float* __restrict__ mlp_w2,
    const float* __restrict__ mlp_w3,
    float* __restrict__ ws)
{
    int idx = blockIdx.x * 256 + threadIdx.x;
    if (idx < 5120) {
        int h = idx >> 6, j = idx & 63;
        ws[WS_S + idx] = att_w1[h*256 + j] + att_w1[h*256 + 128 + j];
    } else if (idx < 62720) {
        int r = idx - 5120;            /* r = k*200 + t */
        int k = r / 200, t = r - k*200;
        ws[WS_W1T + r] = mlp_w1[t*288 + k];
    } else if (idx < 78720) {
        int r = idx - 62720;           /* r = k*80 + g */
        int k = r / 80, g = r - k*80;
        ws[WS_W2T + r] = mlp_w2[g*200 + k];
    } else if (idx < 78880) {
        int r = idx - 78720;           /* r = k*2 + o */
        int k = r >> 1, o = r & 1;
        ws[WS_W3T + r] = mlp_w3[o*80 + k];
    } else if (idx < 78928) {
        int g = idx - 78880;
        ws[WS_W3P + g] = (g < 40) ? att_w3[g] : 0.0f;
    } else if (idx < 89168) {
        /* W1cat fragments: Xcat(200x128) @ W1cat(128x80)
           k<64: beh rows -> w1[:,64:128]-w1[:,128:192]; k>=64: q*beh -> w1[:,192:256] */
        int e  = idx - 78928;
        int nt = e >> 11;
        int ks = (e >> 9) & 3;
        int ln = (e >> 3) & 63;
        int j  = e & 7;
        int n = nt*16 + (ln & 15);
        int k = ks*32 + (ln >> 4)*8 + j;
        float val = (k < 64)
            ? (att_w1[n*256 + 64 + k] - att_w1[n*256 + 128 + k])
            : att_w1[n*256 + 192 + (k - 64)];
        ((u16*)(ws + WS_WF1F))[e] = f2bf(val);
    } else if (idx < 93776) {
        /* W2cat fragments: S1(200x80,pad96) @ W2cat(96x48): W2cat[k][n]=att_w2[n*80+k] */
        int e  = idx - 89168;
        int nt = e / 1536;
        int ks = (e / 512) % 3;
        int ln = (e >> 3) & 63;
        int j  = e & 7;
        int n = nt*16 + (ln & 15);
        int k = ks*32 + (ln >> 4)*8 + j;
        float val = (n < 40 && k < 80) ? att_w2[n*80 + k] : 0.0f;
        ((u16*)(ws + WS_WF2F))[e] = f2bf(val);
    }
}

/* ---- Kernel A: gather + attention + softmax + pooling -> feature row X[b][288] ----
   R11 base (130.4 us best) with wf2_sh removed: LDS 40520 -> 40960 rounded, so
   4 blocks/CU (=160 KiB exactly) IF VGPR <= 128. Keep (256,3) so the allocator
   has slack (R12: a tight cap spills); hardware residency follows actual VGPR.
   WF2 fragments read per-tile from ws (9 independent 16B L2-hit loads, hoisted). */
__global__ __launch_bounds__(256, 3) void din_kernel(
    const int* __restrict__ uid, const int* __restrict__ gid, const int* __restrict__ cid,
    const int* __restrict__ gid_his, const int* __restrict__ cid_his, const int* __restrict__ masks,
    const float* __restrict__ user_emb, const float* __restrict__ good_emb, const float* __restrict__ cat_emb,
    const float* __restrict__ att_b1, const float* __restrict__ att_b2, const float* __restrict__ att_b3,
    const float* __restrict__ ws, float* __restrict__ Xg)
{
    /* Xc[200 rows][64 bf16] with 16B-slot XOR swizzle: slot' = slot ^ (row&7)  (25600 B) */
    __shared__ u16 Xc[200*64];
    /* per-wave S1 scratch: [16 rows][104 bf16] (row stride 208 B, 16B-aligned) */
    __shared__ u16 scr[4*1664];
    __shared__ float q_sh[64];
    __shared__ float c0_sh[80];
    __shared__ float sp_sh[256];
    __shared__ float scal_sh[2];
    /* total 40520 B -> 40960 alloc; 4 blocks/CU */

    /* overlays into scr (only live after the tile loop is done): 1024 floats = 4 KB */
    float* redA  = (float*)scr;       /* [8 qq][64 col] */
    float* redU  = redA + 512;        /* [8 qq][64 col] */

    const int b    = blockIdx.x;
    const int tid  = threadIdx.x;
    const int lane = tid & 63;
    const int wv   = tid >> 6;
    const int lrow = lane & 15;
    const int lgrp = lane >> 4;

    const int* gh = gid_his + b*200;
    const int* ch = cid_his + b*200;

    /* ---- Preload W1cat fragments into registers (loop-invariant): 20 x 16B = 80 VGPR ---- */
    short8 wf1r[20];
    {
        const short8* WF1 = (const short8*)(ws + WS_WF1F);
        #pragma unroll
        for (int i = 0; i < 20; ++i) wf1r[i] = WF1[i*64 + lane];
    }
    const short8* WF2 = (const short8*)(ws + WS_WF2F);

    /* ---- Phase 0/1 fused: gather -> bf16 -> Xc (swizzled) ---- */
    #pragma unroll
    for (int it = 0; it < 12; ++it) {
        int idx = it*256 + tid;
        int l = idx >> 4, c = idx & 15;
        const float* src = (c < 8)
            ? (good_emb + (size_t)gh[l]*32 + (c & 7)*4)
            : (cat_emb  + (size_t)ch[l]*32 + (c & 7)*4);
        float4 v = *(const float4*)src;
        uint2v pk;
        pk[0] = f2bf2(v.x, v.y);
        pk[1] = f2bf2(v.z, v.w);
        int byteoff = l*128 + ((((c >> 1) ^ (l & 7)) << 4)) + ((c & 1) << 3);
        *((uint2v*)((char*)Xc + byteoff)) = pk;
    }
    if (tid < 128) {
        int idx = 3072 + tid;
        int l = idx >> 4, c = idx & 15;
        const float* src = (c < 8)
            ? (good_emb + (size_t)gh[l]*32 + (c & 7)*4)
            : (cat_emb  + (size_t)ch[l]*32 + (c & 7)*4);
        float4 v = *(const float4*)src;
        uint2v pk;
        pk[0] = f2bf2(v.x, v.y);
        pk[1] = f2bf2(v.z, v.w);
        int byteoff = l*128 + ((((c >> 1) ^ (l & 7)) << 4)) + ((c & 1) << 3);
        *((uint2v*)((char*)Xc + byteoff)) = pk;
    }
    if (tid < 64) {
        q_sh[tid] = (tid < 32) ? good_emb[(size_t)gid[b]*32 + tid]
                               : cat_emb[(size_t)cid[b]*32 + (tid - 32)];
    }
    if (tid >= 200 && tid < 256) sp_sh[tid] = NEG_INF_F;
    __syncthreads();

    /* c0[h] = b1[h] + sum_j q_j*(W1[h,j]+W1[h,128+j]); float4 loads */
    if (tid < 80) {
        const float4* Sw = (const float4*)(ws + WS_S + tid*64);
        const float4* q4 = (const float4*)q_sh;
        float u0 = 0.f, u1 = 0.f;
        #pragma unroll
        for (int j = 0; j < 16; j += 2) {
            float4 w0 = Sw[j],   qv0 = q4[j];
            float4 w1 = Sw[j+1], qv1 = q4[j+1];
            u0 += w0.x*qv0.x + w0.y*qv0.y + w0.z*qv0.z + w0.w*qv0.w;
            u1 += w1.x*qv1.x + w1.y*qv1.y + w1.z*qv1.z + w1.w*qv1.w;
        }
        c0_sh[tid] = att_b1[tid] + u0 + u1;
    }
    __syncthreads();

    /* ---- Phase 2: per-M-tile attention MLP via MFMA ---- */
    f32x8 qf0, qf1;
    #pragma unroll
    for (int j = 0; j < 8; ++j) {
        qf0[j] = q_sh[lgrp*8 + j];
        qf1[j] = q_sh[32 + lgrp*8 + j];
    }
    float c0v[5];
    #pragma unroll
    for (int nt = 0; nt < 5; ++nt) c0v[nt] = c0_sh[nt*16 + lrow];
    float b2v[3], w3c[3];
    #pragma unroll
    for (int nt = 0; nt < 3; ++nt) {
        int col = nt*16 + lrow;
        b2v[nt] = (col < 40) ? att_b2[col] : 0.0f;
        w3c[nt] = ws[WS_W3P + col];
    }
    const float bias3 = att_b3[0];

    u16* scr_w = scr + wv*1664;

    /* zero-pad S1 cols 80..95 once (never overwritten by S1 stores) */
    {
        uint2v z; z[0] = 0u; z[1] = 0u;
        *((uint2v*)(scr_w + lrow*104 + 80 + lgrp*4)) = z;
    }

    for (int t = wv; t < 13; t += 4) {
        const int m0 = (t == 12) ? 184 : (t << 4);   /* tile 12 overlaps tile 11: benign same-value race */
        const int m  = m0 + lrow;

        /* A fragments: beh (ks 0,1 from LDS), q*beh (ks 2,3 in-register) */
        short8 A0, A1;
        {
            int sl0 = (0 + lgrp) ^ (m & 7);
            int sl1 = (4 + lgrp) ^ (m & 7);
            A0 = *(const short8*)((const char*)Xc + m*128 + (sl0 << 4));
            A1 = *(const short8*)((const char*)Xc + m*128 + (sl1 << 4));
        }
        short8 A2 = mulqf(A0, qf0);
        short8 A3 = mulqf(A1, qf1);

        /* layer 1: S1(16x80) = sigmoid(Xcat @ W1cat + c0) -> scratch bf16 */
        #pragma unroll
        for (int nt = 0; nt < 5; ++nt) {
            f32x4 acc = {0.f, 0.f, 0.f, 0.f};
            acc = mfma16(A0, wf1r[nt*4 + 0], acc);
            acc = mfma16(A1, wf1r[nt*4 + 1], acc);
            acc = mfma16(A2, wf1r[nt*4 + 2], acc);
            acc = mfma16(A3, wf1r[nt*4 + 3], acc);
            #pragma unroll
            for (int r = 0; r < 4; ++r) {
                float s1v = fsigmoid(acc[r] + c0v[nt]);
                scr_w[(lgrp*4 + r)*104 + nt*16 + lrow] = f2bf(s1v);
            }
        }

        /* layer 2: S2(16x48) accumulators stay in registers; WF2 from L2 (hoistable) */
        short8 B0 = *(const short8*)(scr_w + lrow*104 +  0 + lgrp*8);
        short8 B1 = *(const short8*)(scr_w + lrow*104 + 32 + lgrp*8);
        short8 B2 = *(const short8*)(scr_w + lrow*104 + 64 + lgrp*8);
        f32x4 acc2[3];
        #pragma unroll
        for (int nt = 0; nt < 3; ++nt) {
            f32x4 acc = {0.f, 0.f, 0.f, 0.f};
            acc = mfma16(B0, WF2[(nt*3 + 0)*64 + lane], acc);
            acc = mfma16(B1, WF2[(nt*3 + 1)*64 + lane], acc);
            acc = mfma16(B2, WF2[(nt*3 + 2)*64 + lane], acc);
            acc2[nt] = acc;
        }

        /* layer 3 fully in-register: partial = sum_nt sigmoid(acc2[nt][r]+b2)*w3;
           reduce over 16 lanes (cols) via xor-shfl 1,2,4,8 */
        float v3p[4];
        #pragma unroll
        for (int r = 0; r < 4; ++r) {
            float p = fsigmoid(acc2[0][r] + b2v[0]) * w3c[0]
                    + fsigmoid(acc2[1][r] + b2v[1]) * w3c[1]
                    + fsigmoid(acc2[2][r] + b2v[2]) * w3c[2];
            p += __shfl_xor(p, 1);
            p += __shfl_xor(p, 2);
            p += __shfl_xor(p, 4);
            p += __shfl_xor(p, 8);
            v3p[r] = p;
        }
        if (lrow == 0) {
            #pragma unroll
            for (int r = 0; r < 4; ++r) {
                int mm = m0 + lgrp*4 + r;
                int mk = masks[b*200 + mm];
                sp_sh[mm] = mk ? (v3p[r] + bias3) : NEG_BIG;
            }
        }
    }
    __syncthreads();

    /* ---- Phase 3: masked softmax over l ---- */
    if (tid < 64) {
        float mv = fmaxf(fmaxf(sp_sh[tid], sp_sh[tid+64]), fmaxf(sp_sh[tid+128], sp_sh[tid+192]));
        #pragma unroll
        for (int off = 32; off > 0; off >>= 1) mv = fmaxf(mv, __shfl_down(mv, off));
        if (tid == 0) scal_sh[0] = mv;
    }
    __syncthreads();
    {
        float mx = scal_sh[0];
        float sm = sp_sh[tid];
        float ev = (tid < 200) ? __expf(sm - mx) : 0.0f;
        sp_sh[tid] = ev;
    }
    __syncthreads();
    if (tid < 64) {
        float s = (sp_sh[tid] + sp_sh[tid+64]) + (sp_sh[tid+128] + sp_sh[tid+192]);
        #pragma unroll
        for (int off = 32; off > 0; off >>= 1) s += __shfl_down(s, off);
        if (tid == 0) scal_sh[1] = s;
    }
    __syncthreads();

    /* ---- Phase 4: pooling att (unnormalized) and ubs; paired u32 reads from Xc ---- */
    {
        int j2 = tid & 31;            /* column pair: cols 2j2, 2j2+1 */
        int qq = tid >> 5;            /* 8 row-groups of 25 */
        int slot = j2 >> 2;           /* logical 16B slot = (2j2)>>3 */
        int inb  = (j2 & 3) << 2;     /* byte within slot */
        float a0 = 0.f, a1 = 0.f, u0 = 0.f, u1 = 0.f;
        #pragma unroll 5
        for (int mm = qq*25; mm < qq*25 + 25; ++mm) {
            u32 pr = *(const u32*)((const char*)Xc + mm*128 + (((slot ^ (mm & 7)) << 4)) + inb);
            float b0 = bf2f((u16)pr);
            float b1_ = bf2f((u16)(pr >> 16));
            float w = sp_sh[mm];
            a0 += w*b0; a1 += w*b1_;
            u0 += b0;   u1 += b1_;
        }
        redA[qq*64 + 2*j2]     = a0;
        redA[qq*64 + 2*j2 + 1] = a1;
        redU[qq*64 + 2*j2]     = u0;
        redU[qq*64 + 2*j2 + 1] = u1;
    }
    __syncthreads();

    /* ---- write feature row X[b][288] ---- */
    float inv = 1.0f / scal_sh[1];
    if (tid < 64) {
        float att = 0.f, ub = 0.f;
        #pragma unroll
        for (int qq = 0; qq < 8; ++qq) {
            att += redA[qq*64 + tid];
            ub  += redU[qq*64 + tid];
        }
        att *= inv;
        float qv = q_sh[tid];
        float* xr = Xg + (size_t)b*288;
        xr[32  + tid] = qv;
        xr[96  + tid] = ub;
        xr[160 + tid] = ub * qv;
        xr[224 + tid] = att;
    }
    if (tid >= 64 && tid < 96) {
        Xg[(size_t)b*288 + (tid - 64)] = user_emb[(size_t)uid[b]*32 + (tid - 64)];
    }
}

/* ---- Kernel B: final MLP 288 -> 200 -> 80 -> 2, 8 rows/block x 512 blocks ---- */
__global__ __launch_bounds__(256) void mlp_kernel(
    const float* __restrict__ ws,
    const float* __restrict__ mlp_b1, const float* __restrict__ mlp_b2, const float* __restrict__ mlp_b3,
    const float* __restrict__ pa1, const float* __restrict__ pa2,
    float* __restrict__ out)
{
    __shared__ float h1_sh[8*204];
    __shared__ float h2_sh[8*81];

    const int tid = threadIdx.x;
    const int r0  = blockIdx.x * 8;
    const float* Xg  = ws + WS_XF;
    const float* w1T = ws + WS_W1T;
    const float* w2T = ws + WS_W2T;
    const float* w3T = ws + WS_W3T;

    /* layer 1: thread = neuron n, register-block over 8 rows */
    {
        int n = (tid < 200) ? tid : 199;
        float bias = mlp_b1[n];
        float acc[8];
        #pragma unroll
        for (int r = 0; r < 8; ++r) acc[r] = bias;
        for (int k = 0; k < 288; k += 4) {
            float w0 = w1T[(k+0)*200 + n];
            float w1 = w1T[(k+1)*200 + n];
            float w2 = w1T[(k+2)*200 + n];
            float w3 = w1T[(k+3)*200 + n];
            #pragma unroll
            for (int r = 0; r < 8; ++r) {
                const float4 xv = *(const float4*)(Xg + (size_t)(r0 + r)*288 + k);
                acc[r] += xv.x*w0 + xv.y*w1 + xv.z*w2 + xv.w*w3;
            }
        }
        if (tid < 200) {
            float a = pa1[n];
            #pragma unroll
            for (int r = 0; r < 8; ++r) {
                float v = acc[r];
                h1_sh[r*204 + n] = (v >= 0.f) ? v : a*v;
            }
        }
    }
    __syncthreads();

    /* layer 2: 160 threads: g = tid%80, row-half = (tid/80)*4 (4 rows each) */
    if (tid < 160) {
        int g  = (tid < 80) ? tid : tid - 80;
        int rh = (tid < 80) ? 0 : 4;
        float bias = mlp_b2[g];
        float acc[4];
        #pragma unroll
        for (int r = 0; r < 4; ++r) acc[r] = bias;
        for (int k = 0; k < 200; k += 4) {
            float w0 = w2T[(k+0)*80 + g];
            float w1 = w2T[(k+1)*80 + g];
            float w2 = w2T[(k+2)*80 + g];
            float w3 = w2T[(k+3)*80 + g];
            #pragma unroll
            for (int r = 0; r < 4; ++r) {
                const float4 xv = *(const float4*)(&h1_sh[(rh + r)*204 + k]);
                acc[r] += xv.x*w0 + xv.y*w1 + xv.z*w2 + xv.w*w3;
            }
        }
        float a = pa2[g];
        #pragma unroll
        for (int r = 0; r < 4; ++r) {
            float v = acc[r];
            h2_sh[(rh + r)*81 + g] = (v >= 0.f) ? v : a*v;
        }
    }
    __syncthreads();

    /* layer 3: 16 threads: (row, o) */
    if (tid < 16) {
        int r = tid >> 1, o = tid & 1;
        float acc = mlp_b3[o];
        #pragma unroll 8
        for (int k = 0; k < 80; ++k) acc += h2_sh[r*81 + k] * w3T[k*2 + o];
        out[(size_t)(r0 + r)*2 + o] = acc;
    }
}

extern "C" void kernel_launch(void* const* d_in, const int* in_sizes, int n_in,
                              void* d_out, int out_size, void* d_ws, size_t ws_size,
                              hipStream_t stream) {
    const int*   uid      = (const int*)d_in[0];
    const int*   gid      = (const int*)d_in[1];
    const int*   cid      = (const int*)d_in[2];
    const int*   gid_his  = (const int*)d_in[3];
    const int*   cid_his  = (const int*)d_in[4];
    const int*   masks    = (const int*)d_in[5];
    const float* user_emb = (const float*)d_in[6];
    const float* good_emb = (const float*)d_in[7];
    const float* cat_emb  = (const float*)d_in[8];
    const float* att_w1   = (const float*)d_in[9];
    const float* att_b1   = (const float*)d_in[10];
    const float* att_w2   = (const float*)d_in[11];
    const float* att_b2   = (const float*)d_in[12];
    const float* att_w3   = (const float*)d_in[13];
    const float* att_b3   = (const float*)d_in[14];
    const float* mlp_w1   = (const float*)d_in[15];
    const float* mlp_b1   = (const float*)d_in[16];
    const float* mlp_w2   = (const float*)d_in[17];
    const float* mlp_b2   = (const float*)d_in[18];
    const float* mlp_w3   = (const float*)d_in[19];
    const float* mlp_b3   = (const float*)d_in[20];
    const float* pa1      = (const float*)d_in[21];
    const float* pa2      = (const float*)d_in[22];
    float* ws   = (float*)d_ws;
    float* outp = (float*)d_out;

    hipLaunchKernelGGL(prep_kernel, dim3(367), dim3(256), 0, stream,
                       att_w1, att_w2, att_w3, mlp_w1, mlp_w2, mlp_w3, ws);
    hipLaunchKernelGGL(din_kernel, dim3(4096), dim3(256), 0, stream,
                       uid, gid, cid, gid_his, cid_his, masks,
                       user_emb, good_emb, cat_emb,
                       att_b1, att_b2, att_b3,
                       ws, ws + WS_XF);
    hipLaunchKernelGGL(mlp_kernel, dim3(512), dim3(256), 0, stream,
                       ws, mlp_b1, mlp_b2, mlp_b3, pa1, pa2, outp);
}

// Round 15
// 130.242 us; speedup vs baseline: 1.6889x; 1.1795x over previous
//
#include <hip/hip_runtime.h>
#include <math.h>

typedef unsigned short u16;
typedef unsigned int u32;
typedef __attribute__((ext_vector_type(8))) short short8;
typedef __attribute__((ext_vector_type(8))) float f32x8;
typedef __attribute__((ext_vector_type(4))) float f32x4;
typedef __attribute__((ext_vector_type(2))) unsigned int uint2v;

#define NEG_BIG   (-4294967296.0f)   /* float32(-2^32+1) */
#define NEG_INF_F (-__builtin_inff())

/* ---- workspace layout (float offsets) ---- */
#define WS_S    0        /* [80][64] f32: w1[:,0:64]+w1[:,128:192] (for c0) */
#define WS_W1T  5120     /* [288][200] f32 mlp_w1^T */
#define WS_W2T  62720    /* [200][80]  f32 mlp_w2^T */
#define WS_W3T  78720    /* [80][2]    f32 mlp_w3^T */
#define WS_W3P  78880    /* [48] f32 att_w3 zero-padded */
#define WS_WF1F 78928    /* 10240 bf16: W1cat frags [5 nt][4 ks][64 lane][8] */
#define WS_WF2F 84048    /* 4608 bf16: W2cat frags [3 nt][3 ks][64 lane][8] */
#define WS_XF   86352    /* [4096][288] f32 feature rows (kernel A -> kernel B) */

/* HW packed f32->bf16 RNE (T12/m240: no builtin on gfx950, inline asm is the recipe) */
__device__ __forceinline__ u32 f2bf2(float lo, float hi) {
    u32 r;
    asm("v_cvt_pk_bf16_f32 %0, %1, %2" : "=v"(r) : "v"(lo), "v"(hi));
    return r;
}
__device__ __forceinline__ u16 f2bf(float f) {
    u32 r;
    asm("v_cvt_pk_bf16_f32 %0, %1, %1" : "=v"(r) : "v"(f));
    return (u16)r;
}
__device__ __forceinline__ float bf2f(u16 h) {
    union { u32 u; float f; } v; v.u = ((u32)h) << 16;
    return v.f;
}
/* sigmoid = rcp(1 + 2^(-x*log2e)) : 4 VALU instrs, ~1 ULP */
__device__ __forceinline__ float fsigmoid(float x) {
    float e, r;
    float t = x * -1.44269504088896f;
    asm("v_exp_f32 %0, %1" : "=v"(e) : "v"(t));
    float d = 1.0f + e;
    asm("v_rcp_f32 %0, %1" : "=v"(r) : "v"(d));
    return r;
}
__device__ __forceinline__ short8 mulqf(short8 a, f32x8 qf) {
    union { u32 w[4]; short8 s; } r;
    #pragma unroll
    for (int j = 0; j < 4; ++j) {
        float p0 = bf2f((u16)a[2*j])   * qf[2*j];
        float p1 = bf2f((u16)a[2*j+1]) * qf[2*j+1];
        r.w[j] = f2bf2(p0, p1);
    }
    return r.s;
}
__device__ __forceinline__ f32x4 mfma16(short8 a, short8 b, f32x4 c) {
    return __builtin_amdgcn_mfma_f32_16x16x32_bf16(a, b, c, 0, 0, 0);
}

__global__ __launch_bounds__(256) void prep_kernel(
    const float* __restrict__ att_w1,
    const float* __restrict__ att_w2,
    const float* __restrict__ att_w3,
    const float* __restrict__ mlp_w1,
    const float* __restrict__ mlp_w2,
    const float* __restrict__ mlp_w3,
    float* __restrict__ ws)
{
    int idx = blockIdx.x * 256 + threadIdx.x;
    if (idx < 5120) {
        int h = idx >> 6, j = idx & 63;
        ws[WS_S + idx] = att_w1[h*256 + j] + att_w1[h*256 + 128 + j];
    } else if (idx < 62720) {
        int r = idx - 5120;            /* r = k*200 + t */
        int k = r / 200, t = r - k*200;
        ws[WS_W1T + r] = mlp_w1[t*288 + k];
    } else if (idx < 78720) {
        int r = idx - 62720;           /* r = k*80 + g */
        int k = r / 80, g = r - k*80;
        ws[WS_W2T + r] = mlp_w2[g*200 + k];
    } else if (idx < 78880) {
        int r = idx - 78720;           /* r = k*2 + o */
        int k = r >> 1, o = r & 1;
        ws[WS_W3T + r] = mlp_w3[o*80 + k];
    } else if (idx < 78928) {
        int g = idx - 78880;
        ws[WS_W3P + g] = (g < 40) ? att_w3[g] : 0.0f;
    } else if (idx < 89168) {
        /* W1cat fragments: Xcat(200x128) @ W1cat(128x80)
           k<64: beh rows -> w1[:,64:128]-w1[:,128:192]; k>=64: q*beh -> w1[:,192:256] */
        int e  = idx - 78928;
        int nt = e >> 11;
        int ks = (e >> 9) & 3;
        int ln = (e >> 3) & 63;
        int j  = e & 7;
        int n = nt*16 + (ln & 15);
        int k = ks*32 + (ln >> 4)*8 + j;
        float val = (k < 64)
            ? (att_w1[n*256 + 64 + k] - att_w1[n*256 + 128 + k])
            : att_w1[n*256 + 192 + (k - 64)];
        ((u16*)(ws + WS_WF1F))[e] = f2bf(val);
    } else if (idx < 93776) {
        /* W2cat fragments: S1(200x80,pad96) @ W2cat(96x48): W2cat[k][n]=att_w2[n*80+k] */
        int e  = idx - 89168;
        int nt = e / 1536;
        int ks = (e / 512) % 3;
        int ln = (e >> 3) & 63;
        int j  = e & 7;
        int n = nt*16 + (ln & 15);
        int k = ks*32 + (ln >> 4)*8 + j;
        float val = (n < 40 && k < 80) ? att_w2[n*80 + k] : 0.0f;
        ((u16*)(ws + WS_WF2F))[e] = f2bf(val);
    }
}

/* ---- Kernel A: gather + attention + softmax + pooling -> feature row X[b][288] ----
   Best measured config (R11 = 130.4 us): W1cat in registers (80 VGPR), WF2 in LDS,
   layer 3 in-register; VGPR 84, LDS 50176 -> 3 blocks/CU, no spill.
   Measured dead ends: WF2 in regs + (256,4) spills (R12); 512-thread block loses to
   imbalance/LDS granularity (R13); WF2 from L2 per tile costs ~25 us (R7/R14). */
__global__ __launch_bounds__(256, 3) void din_kernel(
    const int* __restrict__ uid, const int* __restrict__ gid, const int* __restrict__ cid,
    const int* __restrict__ gid_his, const int* __restrict__ cid_his, const int* __restrict__ masks,
    const float* __restrict__ user_emb, const float* __restrict__ good_emb, const float* __restrict__ cat_emb,
    const float* __restrict__ att_b1, const float* __restrict__ att_b2, const float* __restrict__ att_b3,
    const float* __restrict__ ws, float* __restrict__ Xg)
{
    /* Xc[200 rows][64 bf16] with 16B-slot XOR swizzle: slot' = slot ^ (row&7)  (25600 B) */
    __shared__ u16 Xc[200*64];
    /* per-wave S1 scratch: [16 rows][104 bf16] (row stride 208 B, 16B-aligned) */
    __shared__ u16 scr[4*1664];
    /* WF2 fragments staged in LDS: [9 frag][64 lane][8 bf16] = 9216 B */
    __shared__ u16 wf2_sh[9*512];
    __shared__ float q_sh[64];
    __shared__ float c0_sh[80];
    __shared__ float sp_sh[256];
    __shared__ float scal_sh[2];

    /* overlays into scr (only live after the tile loop is done): 1024 floats = 4 KB */
    float* redA  = (float*)scr;       /* [8 qq][64 col] */
    float* redU  = redA + 512;        /* [8 qq][64 col] */

    const int b    = blockIdx.x;
    const int tid  = threadIdx.x;
    const int lane = tid & 63;
    const int wv   = tid >> 6;
    const int lrow = lane & 15;
    const int lgrp = lane >> 4;

    const int* gh = gid_his + b*200;
    const int* ch = cid_his + b*200;

    /* ---- Preload W1cat fragments into registers (loop-invariant): 20 x 16B = 80 VGPR ---- */
    short8 wf1r[20];
    {
        const short8* WF1 = (const short8*)(ws + WS_WF1F);
        #pragma unroll
        for (int i = 0; i < 20; ++i) wf1r[i] = WF1[i*64 + lane];
    }
    /* stage WF2 fragments into LDS (2304 u32, 9 words/thread) */
    {
        const u32* src = (const u32*)(ws + WS_WF2F);
        u32* dst = (u32*)wf2_sh;
        #pragma unroll
        for (int i = 0; i < 9; ++i) dst[i*256 + tid] = src[i*256 + tid];
    }

    /* ---- Phase 0/1 fused: gather -> bf16 -> Xc (swizzled) ---- */
    #pragma unroll
    for (int it = 0; it < 12; ++it) {
        int idx = it*256 + tid;
        int l = idx >> 4, c = idx & 15;
        const float* src = (c < 8)
            ? (good_emb + (size_t)gh[l]*32 + (c & 7)*4)
            : (cat_emb  + (size_t)ch[l]*32 + (c & 7)*4);
        float4 v = *(const float4*)src;
        uint2v pk;
        pk[0] = f2bf2(v.x, v.y);
        pk[1] = f2bf2(v.z, v.w);
        int byteoff = l*128 + ((((c >> 1) ^ (l & 7)) << 4)) + ((c & 1) << 3);
        *((uint2v*)((char*)Xc + byteoff)) = pk;
    }
    if (tid < 128) {
        int idx = 3072 + tid;
        int l = idx >> 4, c = idx & 15;
        const float* src = (c < 8)
            ? (good_emb + (size_t)gh[l]*32 + (c & 7)*4)
            : (cat_emb  + (size_t)ch[l]*32 + (c & 7)*4);
        float4 v = *(const float4*)src;
        uint2v pk;
        pk[0] = f2bf2(v.x, v.y);
        pk[1] = f2bf2(v.z, v.w);
        int byteoff = l*128 + ((((c >> 1) ^ (l & 7)) << 4)) + ((c & 1) << 3);
        *((uint2v*)((char*)Xc + byteoff)) = pk;
    }
    if (tid < 64) {
        q_sh[tid] = (tid < 32) ? good_emb[(size_t)gid[b]*32 + tid]
                               : cat_emb[(size_t)cid[b]*32 + (tid - 32)];
    }
    if (tid >= 200 && tid < 256) sp_sh[tid] = NEG_INF_F;
    __syncthreads();

    /* c0[h] = b1[h] + sum_j q_j*(W1[h,j]+W1[h,128+j]); float4 loads */
    if (tid < 80) {
        const float4* Sw = (const float4*)(ws + WS_S + tid*64);
        const float4* q4 = (const float4*)q_sh;
        float u0 = 0.f, u1 = 0.f;
        #pragma unroll
        for (int j = 0; j < 16; j += 2) {
            float4 w0 = Sw[j],   qv0 = q4[j];
            float4 w1 = Sw[j+1], qv1 = q4[j+1];
            u0 += w0.x*qv0.x + w0.y*qv0.y + w0.z*qv0.z + w0.w*qv0.w;
            u1 += w1.x*qv1.x + w1.y*qv1.y + w1.z*qv1.z + w1.w*qv1.w;
        }
        c0_sh[tid] = att_b1[tid] + u0 + u1;
    }
    __syncthreads();

    /* ---- Phase 2: per-M-tile attention MLP via MFMA ---- */
    f32x8 qf0, qf1;
    #pragma unroll
    for (int j = 0; j < 8; ++j) {
        qf0[j] = q_sh[lgrp*8 + j];
        qf1[j] = q_sh[32 + lgrp*8 + j];
    }
    float c0v[5];
    #pragma unroll
    for (int nt = 0; nt < 5; ++nt) c0v[nt] = c0_sh[nt*16 + lrow];
    float b2v[3], w3c[3];
    #pragma unroll
    for (int nt = 0; nt < 3; ++nt) {
        int col = nt*16 + lrow;
        b2v[nt] = (col < 40) ? att_b2[col] : 0.0f;
        w3c[nt] = ws[WS_W3P + col];
    }
    const float bias3 = att_b3[0];

    u16* scr_w = scr + wv*1664;

    /* zero-pad S1 cols 80..95 once (never overwritten by S1 stores) */
    {
        uint2v z; z[0] = 0u; z[1] = 0u;
        *((uint2v*)(scr_w + lrow*104 + 80 + lgrp*4)) = z;
    }

    for (int t = wv; t < 13; t += 4) {
        const int m0 = (t == 12) ? 184 : (t << 4);   /* tile 12 overlaps tile 11: benign same-value race */
        const int m  = m0 + lrow;

        /* A fragments: beh (ks 0,1 from LDS), q*beh (ks 2,3 in-register) */
        short8 A0, A1;
        {
            int sl0 = (0 + lgrp) ^ (m & 7);
            int sl1 = (4 + lgrp) ^ (m & 7);
            A0 = *(const short8*)((const char*)Xc + m*128 + (sl0 << 4));
            A1 = *(const short8*)((const char*)Xc + m*128 + (sl1 << 4));
        }
        short8 A2 = mulqf(A0, qf0);
        short8 A3 = mulqf(A1, qf1);

        /* layer 1: S1(16x80) = sigmoid(Xcat @ W1cat + c0) -> scratch bf16 */
        #pragma unroll
        for (int nt = 0; nt < 5; ++nt) {
            f32x4 acc = {0.f, 0.f, 0.f, 0.f};
            acc = mfma16(A0, wf1r[nt*4 + 0], acc);
            acc = mfma16(A1, wf1r[nt*4 + 1], acc);
            acc = mfma16(A2, wf1r[nt*4 + 2], acc);
            acc = mfma16(A3, wf1r[nt*4 + 3], acc);
            #pragma unroll
            for (int r = 0; r < 4; ++r) {
                float s1v = fsigmoid(acc[r] + c0v[nt]);
                scr_w[(lgrp*4 + r)*104 + nt*16 + lrow] = f2bf(s1v);
            }
        }

        /* layer 2: S2(16x48) accumulators stay in registers */
        short8 B0 = *(const short8*)(scr_w + lrow*104 +  0 + lgrp*8);
        short8 B1 = *(const short8*)(scr_w + lrow*104 + 32 + lgrp*8);
        short8 B2 = *(const short8*)(scr_w + lrow*104 + 64 + lgrp*8);
        f32x4 acc2[3];
        #pragma unroll
        for (int nt = 0; nt < 3; ++nt) {
            f32x4 acc = {0.f, 0.f, 0.f, 0.f};
            acc = mfma16(B0, *(const short8*)(wf2_sh + ((nt*3 + 0)*64 + lane)*8), acc);
            acc = mfma16(B1, *(const short8*)(wf2_sh + ((nt*3 + 1)*64 + lane)*8), acc);
            acc = mfma16(B2, *(const short8*)(wf2_sh + ((nt*3 + 2)*64 + lane)*8), acc);
            acc2[nt] = acc;
        }

        /* layer 3 fully in-register: partial = sum_nt sigmoid(acc2[nt][r]+b2)*w3;
           reduce over 16 lanes (cols) via xor-shfl 1,2,4,8 */
        float v3p[4];
        #pragma unroll
        for (int r = 0; r < 4; ++r) {
            float p = fsigmoid(acc2[0][r] + b2v[0]) * w3c[0]
                    + fsigmoid(acc2[1][r] + b2v[1]) * w3c[1]
                    + fsigmoid(acc2[2][r] + b2v[2]) * w3c[2];
            p += __shfl_xor(p, 1);
            p += __shfl_xor(p, 2);
            p += __shfl_xor(p, 4);
            p += __shfl_xor(p, 8);
            v3p[r] = p;
        }
        if (lrow == 0) {
            #pragma unroll
            for (int r = 0; r < 4; ++r) {
                int mm = m0 + lgrp*4 + r;
                int mk = masks[b*200 + mm];
                sp_sh[mm] = mk ? (v3p[r] + bias3) : NEG_BIG;
            }
        }
    }
    __syncthreads();

    /* ---- Phase 3: masked softmax over l ---- */
    if (tid < 64) {
        float mv = fmaxf(fmaxf(sp_sh[tid], sp_sh[tid+64]), fmaxf(sp_sh[tid+128], sp_sh[tid+192]));
        #pragma unroll
        for (int off = 32; off > 0; off >>= 1) mv = fmaxf(mv, __shfl_down(mv, off));
        if (tid == 0) scal_sh[0] = mv;
    }
    __syncthreads();
    {
        float mx = scal_sh[0];
        float sm = sp_sh[tid];
        float ev = (tid < 200) ? __expf(sm - mx) : 0.0f;
        sp_sh[tid] = ev;
    }
    __syncthreads();
    if (tid < 64) {
        float s = (sp_sh[tid] + sp_sh[tid+64]) + (sp_sh[tid+128] + sp_sh[tid+192]);
        #pragma unroll
        for (int off = 32; off > 0; off >>= 1) s += __shfl_down(s, off);
        if (tid == 0) scal_sh[1] = s;
    }
    __syncthreads();

    /* ---- Phase 4: pooling att (unnormalized) and ubs; paired u32 reads from Xc ---- */
    {
        int j2 = tid & 31;            /* column pair: cols 2j2, 2j2+1 */
        int qq = tid >> 5;            /* 8 row-groups of 25 */
        int slot = j2 >> 2;           /* logical 16B slot = (2j2)>>3 */
        int inb  = (j2 & 3) << 2;     /* byte within slot */
        float a0 = 0.f, a1 = 0.f, u0 = 0.f, u1 = 0.f;
        #pragma unroll 5
        for (int mm = qq*25; mm < qq*25 + 25; ++mm) {
            u32 pr = *(const u32*)((const char*)Xc + mm*128 + (((slot ^ (mm & 7)) << 4)) + inb);
            float b0 = bf2f((u16)pr);
            float b1_ = bf2f((u16)(pr >> 16));
            float w = sp_sh[mm];
            a0 += w*b0; a1 += w*b1_;
            u0 += b0;   u1 += b1_;
        }
        redA[qq*64 + 2*j2]     = a0;
        redA[qq*64 + 2*j2 + 1] = a1;
        redU[qq*64 + 2*j2]     = u0;
        redU[qq*64 + 2*j2 + 1] = u1;
    }
    __syncthreads();

    /* ---- write feature row X[b][288] ---- */
    float inv = 1.0f / scal_sh[1];
    if (tid < 64) {
        float att = 0.f, ub = 0.f;
        #pragma unroll
        for (int qq = 0; qq < 8; ++qq) {
            att += redA[qq*64 + tid];
            ub  += redU[qq*64 + tid];
        }
        att *= inv;
        float qv = q_sh[tid];
        float* xr = Xg + (size_t)b*288;
        xr[32  + tid] = qv;
        xr[96  + tid] = ub;
        xr[160 + tid] = ub * qv;
        xr[224 + tid] = att;
    }
    if (tid >= 64 && tid < 96) {
        Xg[(size_t)b*288 + (tid - 64)] = user_emb[(size_t)uid[b]*32 + (tid - 64)];
    }
}

/* ---- Kernel B: final MLP 288 -> 200 -> 80 -> 2, 8 rows/block x 512 blocks ---- */
__global__ __launch_bounds__(256) void mlp_kernel(
    const float* __restrict__ ws,
    const float* __restrict__ mlp_b1, const float* __restrict__ mlp_b2, const float* __restrict__ mlp_b3,
    const float* __restrict__ pa1, const float* __restrict__ pa2,
    float* __restrict__ out)
{
    __shared__ float h1_sh[8*204];
    __shared__ float h2_sh[8*81];

    const int tid = threadIdx.x;
    const int r0  = blockIdx.x * 8;
    const float* Xg  = ws + WS_XF;
    const float* w1T = ws + WS_W1T;
    const float* w2T = ws + WS_W2T;
    const float* w3T = ws + WS_W3T;

    /* layer 1: thread = neuron n, register-block over 8 rows */
    {
        int n = (tid < 200) ? tid : 199;
        float bias = mlp_b1[n];
        float acc[8];
        #pragma unroll
        for (int r = 0; r < 8; ++r) acc[r] = bias;
        for (int k = 0; k < 288; k += 4) {
            float w0 = w1T[(k+0)*200 + n];
            float w1 = w1T[(k+1)*200 + n];
            float w2 = w1T[(k+2)*200 + n];
            float w3 = w1T[(k+3)*200 + n];
            #pragma unroll
            for (int r = 0; r < 8; ++r) {
                const float4 xv = *(const float4*)(Xg + (size_t)(r0 + r)*288 + k);
                acc[r] += xv.x*w0 + xv.y*w1 + xv.z*w2 + xv.w*w3;
            }
        }
        if (tid < 200) {
            float a = pa1[n];
            #pragma unroll
            for (int r = 0; r < 8; ++r) {
                float v = acc[r];
                h1_sh[r*204 + n] = (v >= 0.f) ? v : a*v;
            }
        }
    }
    __syncthreads();

    /* layer 2: 160 threads: g = tid%80, row-half = (tid/80)*4 (4 rows each) */
    if (tid < 160) {
        int g  = (tid < 80) ? tid : tid - 80;
        int rh = (tid < 80) ? 0 : 4;
        float bias = mlp_b2[g];
        float acc[4];
        #pragma unroll
        for (int r = 0; r < 4; ++r) acc[r] = bias;
        for (int k = 0; k < 200; k += 4) {
            float w0 = w2T[(k+0)*80 + g];
            float w1 = w2T[(k+1)*80 + g];
            float w2 = w2T[(k+2)*80 + g];
            float w3 = w2T[(k+3)*80 + g];
            #pragma unroll
            for (int r = 0; r < 4; ++r) {
                const float4 xv = *(const float4*)(&h1_sh[(rh + r)*204 + k]);
                acc[r] += xv.x*w0 + xv.y*w1 + xv.z*w2 + xv.w*w3;
            }
        }
        float a = pa2[g];
        #pragma unroll
        for (int r = 0; r < 4; ++r) {
            float v = acc[r];
            h2_sh[(rh + r)*81 + g] = (v >= 0.f) ? v : a*v;
        }
    }
    __syncthreads();

    /* layer 3: 16 threads: (row, o) */
    if (tid < 16) {
        int r = tid >> 1, o = tid & 1;
        float acc = mlp_b3[o];
        #pragma unroll 8
        for (int k = 0; k < 80; ++k) acc += h2_sh[r*81 + k] * w3T[k*2 + o];
        out[(size_t)(r0 + r)*2 + o] = acc;
    }
}

extern "C" void kernel_launch(void* const* d_in, const int* in_sizes, int n_in,
                              void* d_out, int out_size, void* d_ws, size_t ws_size,
                              hipStream_t stream) {
    const int*   uid      = (const int*)d_in[0];
    const int*   gid      = (const int*)d_in[1];
    const int*   cid      = (const int*)d_in[2];
    const int*   gid_his  = (const int*)d_in[3];
    const int*   cid_his  = (const int*)d_in[4];
    const int*   masks    = (const int*)d_in[5];
    const float* user_emb = (const float*)d_in[6];
    const float* good_emb = (const float*)d_in[7];
    const float* cat_emb  = (const float*)d_in[8];
    const float* att_w1   = (const float*)d_in[9];
    const float* att_b1   = (const float*)d_in[10];
    const float* att_w2   = (const float*)d_in[11];
    const float* att_b2   = (const float*)d_in[12];
    const float* att_w3   = (const float*)d_in[13];
    const float* att_b3   = (const float*)d_in[14];
    const float* mlp_w1   = (const float*)d_in[15];
    const float* mlp_b1   = (const float*)d_in[16];
    const float* mlp_w2   = (const float*)d_in[17];
    const float* mlp_b2   = (const float*)d_in[18];
    const float* mlp_w3   = (const float*)d_in[19];
    const float* mlp_b3   = (const float*)d_in[20];
    const float* pa1      = (const float*)d_in[21];
    const float* pa2      = (const float*)d_in[22];
    float* ws   = (float*)d_ws;
    float* outp = (float*)d_out;

    hipLaunchKernelGGL(prep_kernel, dim3(367), dim3(256), 0, stream,
                       att_w1, att_w2, att_w3, mlp_w1, mlp_w2, mlp_w3, ws);
    hipLaunchKernelGGL(din_kernel, dim3(4096), dim3(256), 0, stream,
                       uid, gid, cid, gid_his, cid_his, masks,
                       user_emb, good_emb, cat_emb,
                       att_b1, att_b2, att_b3,
                       ws, ws + WS_XF);
    hipLaunchKernelGGL(mlp_kernel, dim3(512), dim3(256), 0, stream,
                       ws, mlp_b1, mlp_b2, mlp_b3, pa1, pa2, outp);
}